// Round 15
// baseline (62.750 us; speedup 1.0000x reference)
//
#include <hip/hip_runtime.h>
#include <math.h>

#define BB 4
#define CC 256
#define HH 48
#define WI 48
#define NN (HH*WI)      // 2304
#define NHEAD 8
#define HD 32
#define PLANE ((size_t)NN*HD)
#define BUF   (BB*NHEAD*NN*HD)      // 2359296 elems per [9216,256] buffer

typedef unsigned short u16;
typedef __attribute__((ext_vector_type(8))) short bf16x8;
typedef __attribute__((ext_vector_type(4))) float f32x4;

__device__ inline u16 f2bf(float f) {          // RNE float->bf16
  union { float f; unsigned u; } v; v.f = f;
  unsigned r = v.u + 0x7FFFu + ((v.u >> 16) & 1u);
  return (u16)(r >> 16);
}
__device__ inline u16 f2bf_rna(float f) {      // cheap round (f>=0)
  union { float f; unsigned u; } v; v.f = f;
  return (u16)((v.u + 0x8000u) >> 16);
}

// ---------------------------------------------------------------------------
// Fused prep: blocks [0,2304): XT[b*N+n][c] = bf16(x[b][c][n]) transpose tiles
//             blocks [2304,2624): fp32->bf16 weight convert (W1|W2|W3)
// ---------------------------------------------------------------------------
__global__ __launch_bounds__(256) void prep_kernel(
    const float* __restrict__ x, const float* __restrict__ w1,
    const float* __restrict__ w2, const float* __restrict__ w3,
    u16* __restrict__ XT, u16* __restrict__ W1b,
    u16* __restrict__ W2b, u16* __restrict__ W3b) {
  __shared__ float T[32][36];
  const int bx = blockIdx.x;
  const int t = threadIdx.x;
  if (bx < 2304) {
    const int n0 = (bx % 72) * 32, c0 = ((bx / 72) & 7) * 32, b = bx / 576;
    const int c = t >> 3, n4 = (t & 7) * 4;
    *(float4*)&T[c][n4] = *(const float4*)&x[((size_t)b * CC + c0 + c) * NN + n0 + n4];
    __syncthreads();
    const int nn = t >> 3, c4 = (t & 7) * 4;
    ushort4 o;
    o.x = f2bf(T[c4 + 0][nn]); o.y = f2bf(T[c4 + 1][nn]);
    o.z = f2bf(T[c4 + 2][nn]); o.w = f2bf(T[c4 + 3][nn]);
    *(ushort4*)&XT[((size_t)b * NN + n0 + nn) * CC + c0 + c4] = o;
  } else {
    const int i = ((bx - 2304) * 256 + t) * 4;
    const float* src; u16* dst; int off;
    if (i < 196608)      { src = w1; dst = W1b; off = i; }
    else if (i < 262144) { src = w2; dst = W2b; off = i - 196608; }
    else                 { src = w3; dst = W3b; off = i - 262144; }
    float4 v = *(const float4*)&src[off];
    ushort4 o = {f2bf(v.x), f2bf(v.y), f2bf(v.z), f2bf(v.w)};
    *(ushort4*)&dst[off] = o;
  }
}

// ---------------------------------------------------------------------------
// MFMA GEMM core 128x128 (R4/R8-proven, used by qkv): K=256, 4 waves 2x2.
// Frag layout (HW-verified): A row=ll, B col=ll, k=lh*8+j; C/D row=lh*4+r, col=ll.
// ---------------------------------------------------------------------------
__device__ __forceinline__ void gemm_core(
    const u16* __restrict__ act, const u16* __restrict__ wb,
    int m0, int j0, u16 (&As)[128][40], u16 (&Ws)[128][40],
    f32x4 (&acc)[4][4], int tid) {
  const int lane = tid & 63, ll = lane & 15, lh = lane >> 4;
  const int wv = tid >> 6;
  const int wm = (wv >> 1) << 6, wj = (wv & 1) << 6;
  const int r_ = tid >> 1;
  const int kh = (tid & 1) << 4;
  for (int k0 = 0; k0 < CC; k0 += 32) {
    __syncthreads();
    bf16x8 a0 = *(const bf16x8*)&act[(size_t)(m0 + r_) * CC + k0 + kh];
    bf16x8 a1 = *(const bf16x8*)&act[(size_t)(m0 + r_) * CC + k0 + kh + 8];
    bf16x8 w0 = *(const bf16x8*)&wb[(size_t)(j0 + r_) * CC + k0 + kh];
    bf16x8 w1 = *(const bf16x8*)&wb[(size_t)(j0 + r_) * CC + k0 + kh + 8];
    *(bf16x8*)&As[r_][kh]     = a0;
    *(bf16x8*)&As[r_][kh + 8] = a1;
    *(bf16x8*)&Ws[r_][kh]     = w0;
    *(bf16x8*)&Ws[r_][kh + 8] = w1;
    __syncthreads();
    bf16x8 af[4], bfv[4];
#pragma unroll
    for (int s = 0; s < 4; ++s) {
      af[s]  = *(const bf16x8*)&As[wm + s * 16 + ll][lh * 8];
      bfv[s] = *(const bf16x8*)&Ws[wj + s * 16 + ll][lh * 8];
    }
#pragma unroll
    for (int ms = 0; ms < 4; ++ms)
#pragma unroll
      for (int js = 0; js < 4; ++js)
        acc[ms][js] = __builtin_amdgcn_mfma_f32_16x16x32_bf16(af[ms], bfv[js], acc[ms][js], 0, 0, 0);
  }
}

// ---------------------------------------------------------------------------
// MFMA GEMM core 64x64 (outproj/conv). 4 waves 2x2, wave = 32x32. LDS 10 KB.
// ---------------------------------------------------------------------------
__device__ __forceinline__ void gemm_core64(
    const u16* __restrict__ act, const u16* __restrict__ wb,
    int m0, int j0, u16 (&As)[64][40], u16 (&Ws)[64][40],
    f32x4 (&acc)[2][2], int tid) {
  const int lane = tid & 63, ll = lane & 15, lh = lane >> 4;
  const int wv = tid >> 6;
  const int wm = (wv >> 1) << 5, wj = (wv & 1) << 5;
  const bool isW = (tid >= 128);
  const int r_ = (tid & 127) >> 1;
  const int kh = (tid & 1) << 4;
  const u16* src = isW ? &wb[(size_t)(j0 + r_) * CC + kh]
                       : &act[(size_t)(m0 + r_) * CC + kh];
  u16* dst = isW ? &Ws[r_][kh] : &As[r_][kh];
  for (int k0 = 0; k0 < CC; k0 += 32) {
    __syncthreads();
    bf16x8 v0 = *(const bf16x8*)(src + k0);
    bf16x8 v1 = *(const bf16x8*)(src + k0 + 8);
    *(bf16x8*)dst       = v0;
    *(bf16x8*)(dst + 8) = v1;
    __syncthreads();
    bf16x8 af[2], bfv[2];
#pragma unroll
    for (int s = 0; s < 2; ++s) {
      af[s]  = *(const bf16x8*)&As[wm + s * 16 + ll][lh * 8];
      bfv[s] = *(const bf16x8*)&Ws[wj + s * 16 + ll][lh * 8];
    }
#pragma unroll
    for (int ms = 0; ms < 2; ++ms)
#pragma unroll
      for (int js = 0; js < 2; ++js)
        acc[ms][js] = __builtin_amdgcn_mfma_f32_16x16x32_bf16(af[ms], bfv[js], acc[ms][js], 0, 0, 0);
  }
}

// ---------------------------------------------------------------------------
// GEMM 1 (128x128): qkv = XT @ W1^T + b1 -> Q, K [B,H,N,32], VT [B,H,32,N]
// ---------------------------------------------------------------------------
__global__ __launch_bounds__(256) void qkv_gemm(
    const u16* __restrict__ XT, const u16* __restrict__ W1b,
    const float* __restrict__ bias,
    u16* __restrict__ Qb, u16* __restrict__ Kb, u16* __restrict__ VTb) {
  __shared__ u16 As[128][40];
  __shared__ u16 Ws[128][40];
  const int tid = threadIdx.x;
  const int m0 = blockIdx.x * 128, j0 = blockIdx.y * 128;
  f32x4 acc[4][4] = {};
  gemm_core(XT, W1b, m0, j0, As, Ws, acc, tid);

  const int lane = tid & 63, ll = lane & 15, lh = lane >> 4;
  const int wv = tid >> 6;
  const int wm = (wv >> 1) << 6, wj = (wv & 1) << 6;
  const int part = blockIdx.y >> 1;            // 0=Q 1=K 2=V (uniform)
  const int b = m0 / NN, n0 = m0 % NN;
#pragma unroll
  for (int js = 0; js < 4; ++js) {
    const int j = j0 + wj + js * 16 + ll;
    const float bj = bias[j];
    const int head = (j >> 5) & 7, d = j & 31;
#pragma unroll
    for (int ms = 0; ms < 4; ++ms) {
      const int nb = n0 + wm + ms * 16 + (lh << 2);
      if (part == 2) {
        ushort4 v = {f2bf(acc[ms][js][0] + bj), f2bf(acc[ms][js][1] + bj),
                     f2bf(acc[ms][js][2] + bj), f2bf(acc[ms][js][3] + bj)};
        *(ushort4*)&VTb[(((size_t)b * NHEAD + head) * HD + d) * NN + nb] = v;
      } else {
        u16* dst = (part == 0 ? Qb : Kb) + ((size_t)b * NHEAD + head) * PLANE;
#pragma unroll
        for (int r = 0; r < 4; ++r)
          dst[(size_t)(nb + r) * HD + d] = f2bf(acc[ms][js][r] + bj);
      }
    }
  }
}

// ---------------------------------------------------------------------------
// MFMA windowed attention, 16x8 query tile: 8 waves (512 thr), one wave per
// spatial query row. 2-row chunked double-buffered staging (R14-proven wave
// code). 24 staged rows service 8 query rows (vs 20/4) -> staging, barriers
// and prologues per query ~halve. LDS 27.6 KB -> 5 blocks/CU cap >= 2.25
// resident. + s_setprio(1) around compute clusters.
// ---------------------------------------------------------------------------
__global__ __launch_bounds__(512) void attn_mfma(
    const u16* __restrict__ Qb, const u16* __restrict__ Kb,
    const u16* __restrict__ VTb, u16* __restrict__ Ob) {
  __shared__ u16 Ks[2][64][32];   // [buf][slot = rr*32+key][dim]
  __shared__ u16 VTs[2][32][72];  // [buf][dim][slot] (pad 72)
  __shared__ u16 Ps[8][16][40];   // per-wave P [query][keyslot]
  const int bid  = blockIdx.x;
  const int tile = bid % 18;      // 6 (th, 8 rows) x 3 (tw, 16 cols)
  const int head = (bid / 18) & 7;
  const int b    = bid / 144;
  const int th0 = (tile / 3) * 8, tw0 = (tile % 3) * 16;
  const int tid = threadIdx.x;
  const int wv = tid >> 6, lane = tid & 63;
  const int lh = lane >> 4, ll = lane & 15;
  const size_t plane = ((size_t)b * NHEAD + head) * PLANE;

  const int wlo = max(0, tw0 - 8);
  const int nw  = min(WI, tw0 + 24) - wlo;       // 24 or 32, block-uniform
  const int rlo = max(0, th0 - 8), rhi = min(HH, th0 + 16);   // 16 or 24 rows (even)

  const int qh = th0 + wv;                       // wave's query row
  const bf16x8 qfrag = *(const bf16x8*)&Qb[plane + (size_t)(qh * WI + tw0 + ll) * HD + lh * 8];

  // column masks per C/D reg r (query col = tw0 + lh*4 + r)
  int qw_r[4];
  float cb0[4], cb1[4];
  const int wk0 = wlo + ll;            // <= 39, always a real column
  const int wk1 = wlo + 16 + ll;       // may be >= 48 for tw0=32
#pragma unroll
  for (int r = 0; r < 4; ++r) {
    qw_r[r] = tw0 + (lh << 2) + r;
    cb0[r] = (abs(wk0 - qw_r[r]) <= 8) ? 0.0f : -30000.0f;
    cb1[r] = (wk1 < WI && abs(wk1 - qw_r[r]) <= 8) ? 0.0f : -30000.0f;
  }

  f32x4 o0 = {0.f, 0.f, 0.f, 0.f}, o1 = {0.f, 0.f, 0.f, 0.f};
  const f32x4 zf = {0.f, 0.f, 0.f, 0.f};
  float lsum[4] = {0.f, 0.f, 0.f, 0.f};
  // K staging (512 thr): slot = tid>>3 (0..63), d = (tid&7)*4 (ushort4)
  const int sk_slot = tid >> 3, sk_d = (tid & 7) * 4;
  const int sk_rr = sk_slot >> 5, sk_c = sk_slot & 31;
  // VT staging: d = tid>>4 (0..31), slot = (tid&15)*4 (ushort4)
  const int sv_d = tid >> 4, sv_s = (tid & 15) * 4;
  const int sv_rr = sv_s >> 5, sv_c = sv_s & 31;
  const ushort4 zz = {0, 0, 0, 0};
  const float C2 = 0.25501651847296056f;         // (1/sqrt(32)) * log2(e)
  const int nch = (rhi - rlo) >> 1;

  // prologue: stage chunk 0 (rows rlo, rlo+1) into buf 0
  {
    ushort4 kv = zz, vv = zz;
    if (sk_c < nw)
      kv = *(const ushort4*)&Kb[plane + (size_t)((rlo + sk_rr) * WI + wlo + sk_c) * HD + sk_d];
    if (sv_c < nw)
      vv = *(const ushort4*)&VTb[plane + (size_t)sv_d * NN + (rlo + sv_rr) * WI + wlo + sv_c];
    *(ushort4*)&Ks[0][sk_slot][sk_d] = kv;
    *(ushort4*)&VTs[0][sv_d][sv_s] = vv;
  }

  int cur = 0;
  for (int c = 0; c < nch; ++c) {
    const int hk2 = rlo + (c << 1);
    ushort4 nkv = zz, nvv = zz;
    const bool more = (c + 1 < nch);
    if (more) {
      if (sk_c < nw)
        nkv = *(const ushort4*)&Kb[plane + (size_t)((hk2 + 2 + sk_rr) * WI + wlo + sk_c) * HD + sk_d];
      if (sv_c < nw)
        nvv = *(const ushort4*)&VTb[plane + (size_t)sv_d * NN + (hk2 + 2 + sv_rr) * WI + wlo + sv_c];
    }
    __syncthreads();   // buf[cur] complete
#pragma unroll
    for (int rr = 0; rr < 2; ++rr) {
      const int hk = hk2 + rr;
      if (hk >= qh - 8 && hk <= qh + 8) {          // wave-uniform row window
        const int sb = rr << 5;
        __builtin_amdgcn_s_setprio(1);
        const bf16x8 k0 = *(const bf16x8*)&Ks[cur][sb + ll][lh * 8];
        const bf16x8 k1 = *(const bf16x8*)&Ks[cur][sb + 16 + ll][lh * 8];
        f32x4 s0 = __builtin_amdgcn_mfma_f32_16x16x32_bf16(qfrag, k0, zf, 0, 0, 0);
        f32x4 s1 = __builtin_amdgcn_mfma_f32_16x16x32_bf16(qfrag, k1, zf, 0, 0, 0);
#pragma unroll
        for (int r = 0; r < 4; ++r) {
          float e0 = exp2f(fmaf(s0[r], C2, cb0[r]));
          float e1 = exp2f(fmaf(s1[r], C2, cb1[r]));
          lsum[r] += e0 + e1;
          Ps[wv][(lh << 2) + r][ll]      = f2bf_rna(e0);
          Ps[wv][(lh << 2) + r][16 + ll] = f2bf_rna(e1);
        }
        const bf16x8 pa = *(const bf16x8*)&Ps[wv][ll][lh * 8];
        const bf16x8 v0 = *(const bf16x8*)&VTs[cur][ll][sb + lh * 8];
        const bf16x8 v1 = *(const bf16x8*)&VTs[cur][16 + ll][sb + lh * 8];
        o0 = __builtin_amdgcn_mfma_f32_16x16x32_bf16(pa, v0, o0, 0, 0, 0);
        o1 = __builtin_amdgcn_mfma_f32_16x16x32_bf16(pa, v1, o1, 0, 0, 0);
        __builtin_amdgcn_s_setprio(0);
      }
    }
    if (more) {
      *(ushort4*)&Ks[cur ^ 1][sk_slot][sk_d] = nkv;
      *(ushort4*)&VTs[cur ^ 1][sv_d][sv_s] = nvv;
    }
    cur ^= 1;
  }

#pragma unroll
  for (int r = 0; r < 4; ++r) {
    float s = lsum[r];
    s += __shfl_xor(s, 1); s += __shfl_xor(s, 2);
    s += __shfl_xor(s, 4); s += __shfl_xor(s, 8);
    const float inv = 1.0f / s;
    const size_t row = ((size_t)b * NN + qh * WI + qw_r[r]) * CC + head * HD;
    Ob[row + ll]      = f2bf(o0[r] * inv);
    Ob[row + 16 + ll] = f2bf(o1[r] * inv);
  }
}

// ---------------------------------------------------------------------------
// GEMM 2 (64x64 tiles): RES[m][c] = bf16( O @ W2^T + b2 + x[b][c][n] )
// ---------------------------------------------------------------------------
__global__ __launch_bounds__(256) void outproj_gemm(
    const u16* __restrict__ Ob, const u16* __restrict__ W2b,
    const float* __restrict__ bias, const float* __restrict__ x,
    u16* __restrict__ RESb) {
  __shared__ u16 As[64][40];
  __shared__ u16 Ws[64][40];
  const int tid = threadIdx.x;
  const int m0 = blockIdx.x * 64, j0 = blockIdx.y * 64;
  f32x4 acc[2][2] = {};
  gemm_core64(Ob, W2b, m0, j0, As, Ws, acc, tid);

  const int lane = tid & 63, ll = lane & 15, lh = lane >> 4;
  const int wv = tid >> 6;
  const int wm = (wv >> 1) << 5, wj = (wv & 1) << 5;
  const int b = m0 / NN, n0 = m0 % NN;
#pragma unroll
  for (int js = 0; js < 2; ++js) {
    const int j = j0 + wj + js * 16 + ll;
    const float bj = bias[j];
#pragma unroll
    for (int ms = 0; ms < 2; ++ms) {
      const int nb = n0 + wm + ms * 16 + (lh << 2);
      float4 xr = *(const float4*)&x[((size_t)b * CC + j) * NN + nb];
      float rr[4] = {acc[ms][js][0] + bj + xr.x, acc[ms][js][1] + bj + xr.y,
                     acc[ms][js][2] + bj + xr.z, acc[ms][js][3] + bj + xr.w};
#pragma unroll
      for (int r = 0; r < 4; ++r)
        RESb[(size_t)(m0 + wm + ms * 16 + (lh << 2) + r) * CC + j] = f2bf(rr[r]);
    }
  }
}

// ---------------------------------------------------------------------------
// GEMM 3 (64x64 tiles): out[b][c][n] = relu( RES @ W3^T + b3 )  (fp32 output)
// ---------------------------------------------------------------------------
__global__ __launch_bounds__(256) void conv_gemm(
    const u16* __restrict__ RESb, const u16* __restrict__ W3b,
    const float* __restrict__ bias, float* __restrict__ out) {
  __shared__ u16 As[64][40];
  __shared__ u16 Ws[64][40];
  const int tid = threadIdx.x;
  const int m0 = blockIdx.x * 64, j0 = blockIdx.y * 64;
  f32x4 acc[2][2] = {};
  gemm_core64(RESb, W3b, m0, j0, As, Ws, acc, tid);

  const int lane = tid & 63, ll = lane & 15, lh = lane >> 4;
  const int wv = tid >> 6;
  const int wm = (wv >> 1) << 5, wj = (wv & 1) << 5;
  const int b = m0 / NN, n0 = m0 % NN;
#pragma unroll
  for (int js = 0; js < 2; ++js) {
    const int j = j0 + wj + js * 16 + ll;
    const float bj = bias[j];
#pragma unroll
    for (int ms = 0; ms < 2; ++ms) {
      const int nb = n0 + wm + ms * 16 + (lh << 2);
      float4 v;
      v.x = fmaxf(acc[ms][js][0] + bj, 0.0f);
      v.y = fmaxf(acc[ms][js][1] + bj, 0.0f);
      v.z = fmaxf(acc[ms][js][2] + bj, 0.0f);
      v.w = fmaxf(acc[ms][js][3] + bj, 0.0f);
      *(float4*)&out[((size_t)b * CC + j) * NN + nb] = v;
    }
  }
}

extern "C" void kernel_launch(void* const* d_in, const int* in_sizes, int n_in,
                              void* d_out, int out_size, void* d_ws, size_t ws_size,
                              hipStream_t stream) {
  const float* x         = (const float*)d_in[0];
  const float* in_proj_w = (const float*)d_in[1];
  const float* in_proj_b = (const float*)d_in[2];
  const float* out_w     = (const float*)d_in[3];
  const float* out_b     = (const float*)d_in[4];
  const float* conv_w    = (const float*)d_in[5];
  const float* conv_b    = (const float*)d_in[6];
  float* out = (float*)d_out;

  u16* wsb = (u16*)d_ws;
  u16* XT   = wsb;                         // [9216][256] bf16
  u16* Qb   = wsb + (size_t)BUF;           // [B,H,N,32]
  u16* Kb   = wsb + (size_t)2 * BUF;       // [B,H,N,32]
  u16* VTb  = wsb + (size_t)3 * BUF;       // [B,H,32,N]
  u16* Ob   = wsb + (size_t)4 * BUF;       // [9216][256]
  u16* RESb = wsb + (size_t)5 * BUF;       // [9216][256]
  u16* W1b  = wsb + (size_t)6 * BUF;       // [768][256]
  u16* W2b  = W1b + 196608;                // [256][256]
  u16* W3b  = W2b + 65536;                 // [256][256]

  prep_kernel<<<dim3(2624), dim3(256), 0, stream>>>(x, in_proj_w, out_w, conv_w,
                                                    XT, W1b, W2b, W3b);
  qkv_gemm<<<dim3(72, 6), dim3(256), 0, stream>>>(XT, W1b, in_proj_b, Qb, Kb, VTb);
  attn_mfma<<<dim3(576), dim3(512), 0, stream>>>(Qb, Kb, VTb, Ob);
  outproj_gemm<<<dim3(144, 4), dim3(256), 0, stream>>>(Ob, W2b, out_b, x, RESb);
  conv_gemm<<<dim3(144, 4), dim3(256), 0, stream>>>(RESb, W3b, conv_b, out);
}

// Round 16
// 62.219 us; speedup vs baseline: 1.0085x; 1.0085x over previous
//
#include <hip/hip_runtime.h>
#include <math.h>

#define BB 4
#define CC 256
#define HH 48
#define WI 48
#define NN (HH*WI)      // 2304
#define NHEAD 8
#define HD 32
#define PLANE ((size_t)NN*HD)
#define BUF   (BB*NHEAD*NN*HD)      // 2359296 elems per [9216,256] buffer

typedef unsigned short u16;
typedef __attribute__((ext_vector_type(8))) short bf16x8;
typedef __attribute__((ext_vector_type(4))) float f32x4;

__device__ inline u16 f2bf(float f) {          // RNE float->bf16
  union { float f; unsigned u; } v; v.f = f;
  unsigned r = v.u + 0x7FFFu + ((v.u >> 16) & 1u);
  return (u16)(r >> 16);
}
__device__ inline u16 f2bf_rna(float f) {      // cheap round (f>=0)
  union { float f; unsigned u; } v; v.f = f;
  return (u16)((v.u + 0x8000u) >> 16);
}

// ---------------------------------------------------------------------------
// Fused prep: blocks [0,2304): XT[b*N+n][c] = bf16(x[b][c][n]) transpose tiles
//             blocks [2304,2624): fp32->bf16 weight convert (W1|W2|W3)
// ---------------------------------------------------------------------------
__global__ __launch_bounds__(256) void prep_kernel(
    const float* __restrict__ x, const float* __restrict__ w1,
    const float* __restrict__ w2, const float* __restrict__ w3,
    u16* __restrict__ XT, u16* __restrict__ W1b,
    u16* __restrict__ W2b, u16* __restrict__ W3b) {
  __shared__ float T[32][36];
  const int bx = blockIdx.x;
  const int t = threadIdx.x;
  if (bx < 2304) {
    const int n0 = (bx % 72) * 32, c0 = ((bx / 72) & 7) * 32, b = bx / 576;
    const int c = t >> 3, n4 = (t & 7) * 4;
    *(float4*)&T[c][n4] = *(const float4*)&x[((size_t)b * CC + c0 + c) * NN + n0 + n4];
    __syncthreads();
    const int nn = t >> 3, c4 = (t & 7) * 4;
    ushort4 o;
    o.x = f2bf(T[c4 + 0][nn]); o.y = f2bf(T[c4 + 1][nn]);
    o.z = f2bf(T[c4 + 2][nn]); o.w = f2bf(T[c4 + 3][nn]);
    *(ushort4*)&XT[((size_t)b * NN + n0 + nn) * CC + c0 + c4] = o;
  } else {
    const int i = ((bx - 2304) * 256 + t) * 4;
    const float* src; u16* dst; int off;
    if (i < 196608)      { src = w1; dst = W1b; off = i; }
    else if (i < 262144) { src = w2; dst = W2b; off = i - 196608; }
    else                 { src = w3; dst = W3b; off = i - 262144; }
    float4 v = *(const float4*)&src[off];
    ushort4 o = {f2bf(v.x), f2bf(v.y), f2bf(v.z), f2bf(v.w)};
    *(ushort4*)&dst[off] = o;
  }
}

// ---------------------------------------------------------------------------
// MFMA GEMM core 128x128 (R4/R8-proven, used by qkv): K=256, 4 waves 2x2.
// Frag layout (HW-verified): A row=ll, B col=ll, k=lh*8+j; C/D row=lh*4+r, col=ll.
// ---------------------------------------------------------------------------
__device__ __forceinline__ void gemm_core(
    const u16* __restrict__ act, const u16* __restrict__ wb,
    int m0, int j0, u16 (*As)[40], u16 (*Ws)[40],
    f32x4 (&acc)[4][4], int tid) {
  const int lane = tid & 63, ll = lane & 15, lh = lane >> 4;
  const int wv = tid >> 6;
  const int wm = (wv >> 1) << 6, wj = (wv & 1) << 6;
  const int r_ = tid >> 1;
  const int kh = (tid & 1) << 4;
  for (int k0 = 0; k0 < CC; k0 += 32) {
    __syncthreads();
    bf16x8 a0 = *(const bf16x8*)&act[(size_t)(m0 + r_) * CC + k0 + kh];
    bf16x8 a1 = *(const bf16x8*)&act[(size_t)(m0 + r_) * CC + k0 + kh + 8];
    bf16x8 w0 = *(const bf16x8*)&wb[(size_t)(j0 + r_) * CC + k0 + kh];
    bf16x8 w1 = *(const bf16x8*)&wb[(size_t)(j0 + r_) * CC + k0 + kh + 8];
    *(bf16x8*)&As[r_][kh]     = a0;
    *(bf16x8*)&As[r_][kh + 8] = a1;
    *(bf16x8*)&Ws[r_][kh]     = w0;
    *(bf16x8*)&Ws[r_][kh + 8] = w1;
    __syncthreads();
    bf16x8 af[4], bfv[4];
#pragma unroll
    for (int s = 0; s < 4; ++s) {
      af[s]  = *(const bf16x8*)&As[wm + s * 16 + ll][lh * 8];
      bfv[s] = *(const bf16x8*)&Ws[wj + s * 16 + ll][lh * 8];
    }
#pragma unroll
    for (int ms = 0; ms < 4; ++ms)
#pragma unroll
      for (int js = 0; js < 4; ++js)
        acc[ms][js] = __builtin_amdgcn_mfma_f32_16x16x32_bf16(af[ms], bfv[js], acc[ms][js], 0, 0, 0);
  }
}

// ---------------------------------------------------------------------------
// MFMA GEMM core 64x64 (outproj/conv). 4 waves 2x2, wave = 32x32. LDS 10 KB.
// ---------------------------------------------------------------------------
__device__ __forceinline__ void gemm_core64(
    const u16* __restrict__ act, const u16* __restrict__ wb,
    int m0, int j0, u16 (&As)[64][40], u16 (&Ws)[64][40],
    f32x4 (&acc)[2][2], int tid) {
  const int lane = tid & 63, ll = lane & 15, lh = lane >> 4;
  const int wv = tid >> 6;
  const int wm = (wv >> 1) << 5, wj = (wv & 1) << 5;
  const bool isW = (tid >= 128);
  const int r_ = (tid & 127) >> 1;
  const int kh = (tid & 1) << 4;
  const u16* src = isW ? &wb[(size_t)(j0 + r_) * CC + kh]
                       : &act[(size_t)(m0 + r_) * CC + kh];
  u16* dst = isW ? &Ws[r_][kh] : &As[r_][kh];
  for (int k0 = 0; k0 < CC; k0 += 32) {
    __syncthreads();
    bf16x8 v0 = *(const bf16x8*)(src + k0);
    bf16x8 v1 = *(const bf16x8*)(src + k0 + 8);
    *(bf16x8*)dst       = v0;
    *(bf16x8*)(dst + 8) = v1;
    __syncthreads();
    bf16x8 af[2], bfv[2];
#pragma unroll
    for (int s = 0; s < 2; ++s) {
      af[s]  = *(const bf16x8*)&As[wm + s * 16 + ll][lh * 8];
      bfv[s] = *(const bf16x8*)&Ws[wj + s * 16 + ll][lh * 8];
    }
#pragma unroll
    for (int ms = 0; ms < 2; ++ms)
#pragma unroll
      for (int js = 0; js < 2; ++js)
        acc[ms][js] = __builtin_amdgcn_mfma_f32_16x16x32_bf16(af[ms], bfv[js], acc[ms][js], 0, 0, 0);
  }
}

// ---------------------------------------------------------------------------
// GEMM 1 (128x128): qkv = XT @ W1^T + b1 -> Q, K [B,H,N,32], VT [B,H,32,N]
// Q/K epilogue: LDS-transpose (reusing staging buffer) -> coalesced b128
// stores (replaces 64 scalar 2B stores/thread).
// ---------------------------------------------------------------------------
__global__ __launch_bounds__(256) void qkv_gemm(
    const u16* __restrict__ XT, const u16* __restrict__ W1b,
    const float* __restrict__ bias,
    u16* __restrict__ Qb, u16* __restrict__ Kb, u16* __restrict__ VTb) {
  __shared__ u16 smem[10240];     // As[128][40] + Ws[128][40]; reused as T[128][72]
  u16 (*As)[40] = (u16(*)[40])smem;
  u16 (*Ws)[40] = (u16(*)[40])&smem[5120];
  const int tid = threadIdx.x;
  const int m0 = blockIdx.x * 128, j0 = blockIdx.y * 128;
  f32x4 acc[4][4] = {};
  gemm_core(XT, W1b, m0, j0, As, Ws, acc, tid);

  const int lane = tid & 63, ll = lane & 15, lh = lane >> 4;
  const int wv = tid >> 6;
  const int wm = (wv >> 1) << 6, wj = (wv & 1) << 6;
  const int part = blockIdx.y >> 1;            // 0=Q 1=K 2=V (uniform)
  const int b = m0 / NN, n0 = m0 % NN;

  if (part == 2) {
#pragma unroll
    for (int js = 0; js < 4; ++js) {
      const int j = j0 + wj + js * 16 + ll;
      const float bj = bias[j];
      const int head = (j >> 5) & 7, d = j & 31;
#pragma unroll
      for (int ms = 0; ms < 4; ++ms) {
        const int nb = n0 + wm + ms * 16 + (lh << 2);
        ushort4 v = {f2bf(acc[ms][js][0] + bj), f2bf(acc[ms][js][1] + bj),
                     f2bf(acc[ms][js][2] + bj), f2bf(acc[ms][js][3] + bj)};
        *(ushort4*)&VTb[(((size_t)b * NHEAD + head) * HD + d) * NN + nb] = v;
      }
    }
  } else {
    u16 (*T)[72] = (u16(*)[72])smem;           // 128*72*2 = 18.4 KB, rows 16B-aligned
    u16* dstbase = (part == 0 ? Qb : Kb) + (size_t)b * NHEAD * PLANE;
    const int mrow = tid >> 1, half = tid & 1;
#pragma unroll
    for (int p = 0; p < 2; ++p) {
      __syncthreads();                         // T region free (core reads / prev stores done)
#pragma unroll
      for (int js = 2 * p; js < 2 * p + 2; ++js) {
        const int jj = (wj >> 1) + ((js & 1) << 4) + ll;     // 0..63 within phase
        const float bj = bias[j0 + wj + js * 16 + ll];
#pragma unroll
        for (int ms = 0; ms < 4; ++ms)
#pragma unroll
          for (int r = 0; r < 4; ++r)
            T[wm + ms * 16 + (lh << 2) + r][jj] = f2bf(acc[ms][js][r] + bj);
      }
      __syncthreads();
      const int head = ((j0 >> 5) + (half << 1) + p) & 7;
      const u16* trow = &T[mrow][half << 5];
      u16* drow = dstbase + head * PLANE + (size_t)(n0 + mrow) * HD;
#pragma unroll
      for (int i = 0; i < 4; ++i)
        *(bf16x8*)(drow + i * 8) = *(const bf16x8*)(trow + i * 8);
    }
  }
}

// ---------------------------------------------------------------------------
// MFMA windowed attention (R14-proven BEST): 16x4 query tile, 2-row chunked
// double-buffered staging, 16B/lane staging, setprio around compute.
// LDS 22.3 KB -> 7 blocks/CU cap >= 4.5 resident avg.
// ---------------------------------------------------------------------------
__global__ __launch_bounds__(256) void attn_mfma(
    const u16* __restrict__ Qb, const u16* __restrict__ Kb,
    const u16* __restrict__ VTb, u16* __restrict__ Ob) {
  __shared__ u16 Ks[2][64][32];   // [buf][slot = rr*32+key][dim]
  __shared__ u16 VTs[2][32][72];  // [buf][dim][slot] (pad 72)
  __shared__ u16 Ps[4][16][40];   // per-wave P [query][keyslot]
  const int bid  = blockIdx.x;
  const int tile = bid % 36;      // 12 (th) x 3 (tw)
  const int head = (bid / 36) & 7;
  const int b    = bid / 288;
  const int th0 = (tile / 3) * 4, tw0 = (tile % 3) * 16;
  const int tid = threadIdx.x;
  const int wv = tid >> 6, lane = tid & 63;
  const int lh = lane >> 4, ll = lane & 15;
  const size_t plane = ((size_t)b * NHEAD + head) * PLANE;

  const int wlo = max(0, tw0 - 8);
  const int nw  = min(WI, tw0 + 24) - wlo;       // 24 or 32, block-uniform
  const int rlo = max(0, th0 - 8), rhi = min(HH, th0 + 12);   // even count

  const int qh = th0 + wv;                       // wave's query row
  const bf16x8 qfrag = *(const bf16x8*)&Qb[plane + (size_t)(qh * WI + tw0 + ll) * HD + lh * 8];

  int qw_r[4];
  float cb0[4], cb1[4];
  const int wk0 = wlo + ll;
  const int wk1 = wlo + 16 + ll;
#pragma unroll
  for (int r = 0; r < 4; ++r) {
    qw_r[r] = tw0 + (lh << 2) + r;
    cb0[r] = (abs(wk0 - qw_r[r]) <= 8) ? 0.0f : -30000.0f;
    cb1[r] = (wk1 < WI && abs(wk1 - qw_r[r]) <= 8) ? 0.0f : -30000.0f;
  }

  f32x4 o0 = {0.f, 0.f, 0.f, 0.f}, o1 = {0.f, 0.f, 0.f, 0.f};
  const f32x4 zf = {0.f, 0.f, 0.f, 0.f};
  float lsum[4] = {0.f, 0.f, 0.f, 0.f};
  const int sk_slot = tid >> 2, sk_d = (tid & 3) * 8;
  const int sk_rr = sk_slot >> 5, sk_c = sk_slot & 31;
  const int sv_d = tid >> 3, sv_s = (tid & 7) * 8;
  const int sv_rr = sv_s >> 5, sv_c = sv_s & 31;
  const bf16x8 zz8 = {0, 0, 0, 0, 0, 0, 0, 0};
  const float C2 = 0.25501651847296056f;         // (1/sqrt(32)) * log2(e)
  const int nch = (rhi - rlo) >> 1;

  {
    bf16x8 kv = zz8, vv = zz8;
    if (sk_c < nw)
      kv = *(const bf16x8*)&Kb[plane + (size_t)((rlo + sk_rr) * WI + wlo + sk_c) * HD + sk_d];
    if (sv_c < nw)
      vv = *(const bf16x8*)&VTb[plane + (size_t)sv_d * NN + (rlo + sv_rr) * WI + wlo + sv_c];
    *(bf16x8*)&Ks[0][sk_slot][sk_d] = kv;
    *(bf16x8*)&VTs[0][sv_d][sv_s] = vv;
  }

  int cur = 0;
  for (int c = 0; c < nch; ++c) {
    const int hk2 = rlo + (c << 1);
    bf16x8 nkv = zz8, nvv = zz8;
    const bool more = (c + 1 < nch);
    if (more) {
      if (sk_c < nw)
        nkv = *(const bf16x8*)&Kb[plane + (size_t)((hk2 + 2 + sk_rr) * WI + wlo + sk_c) * HD + sk_d];
      if (sv_c < nw)
        nvv = *(const bf16x8*)&VTb[plane + (size_t)sv_d * NN + (hk2 + 2 + sv_rr) * WI + wlo + sv_c];
    }
    __syncthreads();   // buf[cur] complete
#pragma unroll
    for (int rr = 0; rr < 2; ++rr) {
      const int hk = hk2 + rr;
      if (hk >= qh - 8 && hk <= qh + 8) {          // wave-uniform row window
        const int sb = rr << 5;
        __builtin_amdgcn_s_setprio(1);
        const bf16x8 k0 = *(const bf16x8*)&Ks[cur][sb + ll][lh * 8];
        const bf16x8 k1 = *(const bf16x8*)&Ks[cur][sb + 16 + ll][lh * 8];
        f32x4 s0 = __builtin_amdgcn_mfma_f32_16x16x32_bf16(qfrag, k0, zf, 0, 0, 0);
        f32x4 s1 = __builtin_amdgcn_mfma_f32_16x16x32_bf16(qfrag, k1, zf, 0, 0, 0);
#pragma unroll
        for (int r = 0; r < 4; ++r) {
          float e0 = exp2f(fmaf(s0[r], C2, cb0[r]));
          float e1 = exp2f(fmaf(s1[r], C2, cb1[r]));
          lsum[r] += e0 + e1;
          Ps[wv][(lh << 2) + r][ll]      = f2bf_rna(e0);
          Ps[wv][(lh << 2) + r][16 + ll] = f2bf_rna(e1);
        }
        const bf16x8 pa = *(const bf16x8*)&Ps[wv][ll][lh * 8];
        const bf16x8 v0 = *(const bf16x8*)&VTs[cur][ll][sb + lh * 8];
        const bf16x8 v1 = *(const bf16x8*)&VTs[cur][16 + ll][sb + lh * 8];
        o0 = __builtin_amdgcn_mfma_f32_16x16x32_bf16(pa, v0, o0, 0, 0, 0);
        o1 = __builtin_amdgcn_mfma_f32_16x16x32_bf16(pa, v1, o1, 0, 0, 0);
        __builtin_amdgcn_s_setprio(0);
      }
    }
    if (more) {
      *(bf16x8*)&Ks[cur ^ 1][sk_slot][sk_d] = nkv;
      *(bf16x8*)&VTs[cur ^ 1][sv_d][sv_s] = nvv;
    }
    cur ^= 1;
  }

#pragma unroll
  for (int r = 0; r < 4; ++r) {
    float s = lsum[r];
    s += __shfl_xor(s, 1); s += __shfl_xor(s, 2);
    s += __shfl_xor(s, 4); s += __shfl_xor(s, 8);
    const float inv = 1.0f / s;
    const size_t row = ((size_t)b * NN + qh * WI + qw_r[r]) * CC + head * HD;
    Ob[row + ll]      = f2bf(o0[r] * inv);
    Ob[row + 16 + ll] = f2bf(o1[r] * inv);
  }
}

// ---------------------------------------------------------------------------
// GEMM 2 (64x64 tiles): RES[m][c] = bf16( O @ W2^T + b2 + x[b][c][n] )
// ---------------------------------------------------------------------------
__global__ __launch_bounds__(256) void outproj_gemm(
    const u16* __restrict__ Ob, const u16* __restrict__ W2b,
    const float* __restrict__ bias, const float* __restrict__ x,
    u16* __restrict__ RESb) {
  __shared__ u16 As[64][40];
  __shared__ u16 Ws[64][40];
  const int tid = threadIdx.x;
  const int m0 = blockIdx.x * 64, j0 = blockIdx.y * 64;
  f32x4 acc[2][2] = {};
  gemm_core64(Ob, W2b, m0, j0, As, Ws, acc, tid);

  const int lane = tid & 63, ll = lane & 15, lh = lane >> 4;
  const int wv = tid >> 6;
  const int wm = (wv >> 1) << 5, wj = (wv & 1) << 5;
  const int b = m0 / NN, n0 = m0 % NN;
#pragma unroll
  for (int js = 0; js < 2; ++js) {
    const int j = j0 + wj + js * 16 + ll;
    const float bj = bias[j];
#pragma unroll
    for (int ms = 0; ms < 2; ++ms) {
      const int nb = n0 + wm + ms * 16 + (lh << 2);
      float4 xr = *(const float4*)&x[((size_t)b * CC + j) * NN + nb];
      float rr[4] = {acc[ms][js][0] + bj + xr.x, acc[ms][js][1] + bj + xr.y,
                     acc[ms][js][2] + bj + xr.z, acc[ms][js][3] + bj + xr.w};
#pragma unroll
      for (int r = 0; r < 4; ++r)
        RESb[(size_t)(m0 + wm + ms * 16 + (lh << 2) + r) * CC + j] = f2bf(rr[r]);
    }
  }
}

// ---------------------------------------------------------------------------
// GEMM 3 (64x64 tiles): out[b][c][n] = relu( RES @ W3^T + b3 )  (fp32 output)
// ---------------------------------------------------------------------------
__global__ __launch_bounds__(256) void conv_gemm(
    const u16* __restrict__ RESb, const u16* __restrict__ W3b,
    const float* __restrict__ bias, float* __restrict__ out) {
  __shared__ u16 As[64][40];
  __shared__ u16 Ws[64][40];
  const int tid = threadIdx.x;
  const int m0 = blockIdx.x * 64, j0 = blockIdx.y * 64;
  f32x4 acc[2][2] = {};
  gemm_core64(RESb, W3b, m0, j0, As, Ws, acc, tid);

  const int lane = tid & 63, ll = lane & 15, lh = lane >> 4;
  const int wv = tid >> 6;
  const int wm = (wv >> 1) << 5, wj = (wv & 1) << 5;
  const int b = m0 / NN, n0 = m0 % NN;
#pragma unroll
  for (int js = 0; js < 2; ++js) {
    const int j = j0 + wj + js * 16 + ll;
    const float bj = bias[j];
#pragma unroll
    for (int ms = 0; ms < 2; ++ms) {
      const int nb = n0 + wm + ms * 16 + (lh << 2);
      float4 v;
      v.x = fmaxf(acc[ms][js][0] + bj, 0.0f);
      v.y = fmaxf(acc[ms][js][1] + bj, 0.0f);
      v.z = fmaxf(acc[ms][js][2] + bj, 0.0f);
      v.w = fmaxf(acc[ms][js][3] + bj, 0.0f);
      *(float4*)&out[((size_t)b * CC + j) * NN + nb] = v;
    }
  }
}

extern "C" void kernel_launch(void* const* d_in, const int* in_sizes, int n_in,
                              void* d_out, int out_size, void* d_ws, size_t ws_size,
                              hipStream_t stream) {
  const float* x         = (const float*)d_in[0];
  const float* in_proj_w = (const float*)d_in[1];
  const float* in_proj_b = (const float*)d_in[2];
  const float* out_w     = (const float*)d_in[3];
  const float* out_b     = (const float*)d_in[4];
  const float* conv_w    = (const float*)d_in[5];
  const float* conv_b    = (const float*)d_in[6];
  float* out = (float*)d_out;

  u16* wsb = (u16*)d_ws;
  u16* XT   = wsb;                         // [9216][256] bf16
  u16* Qb   = wsb + (size_t)BUF;           // [B,H,N,32]
  u16* Kb   = wsb + (size_t)2 * BUF;       // [B,H,N,32]
  u16* VTb  = wsb + (size_t)3 * BUF;       // [B,H,32,N]
  u16* Ob   = wsb + (size_t)4 * BUF;       // [9216][256]
  u16* RESb = wsb + (size_t)5 * BUF;       // [9216][256]
  u16* W1b  = wsb + (size_t)6 * BUF;       // [768][256]
  u16* W2b  = W1b + 196608;                // [256][256]
  u16* W3b  = W2b + 65536;                 // [256][256]

  prep_kernel<<<dim3(2624), dim3(256), 0, stream>>>(x, in_proj_w, out_w, conv_w,
                                                    XT, W1b, W2b, W3b);
  qkv_gemm<<<dim3(72, 6), dim3(256), 0, stream>>>(XT, W1b, in_proj_b, Qb, Kb, VTb);
  attn_mfma<<<dim3(1152), dim3(256), 0, stream>>>(Qb, Kb, VTb, Ob);
  outproj_gemm<<<dim3(144, 4), dim3(256), 0, stream>>>(Ob, W2b, out_b, x, RESb);
  conv_gemm<<<dim3(144, 4), dim3(256), 0, stream>>>(RESb, W3b, conv_b, out);
}

// Round 17
// 58.367 us; speedup vs baseline: 1.0751x; 1.0660x over previous
//
#include <hip/hip_runtime.h>
#include <math.h>

#define BB 4
#define CC 256
#define HH 48
#define WI 48
#define NN (HH*WI)      // 2304
#define NHEAD 8
#define HD 32
#define PLANE ((size_t)NN*HD)
#define BUF   (BB*NHEAD*NN*HD)      // 2359296 elems per [9216,256] buffer

typedef unsigned short u16;
typedef __attribute__((ext_vector_type(8))) short bf16x8;
typedef __attribute__((ext_vector_type(4))) float f32x4;

__device__ inline u16 f2bf(float f) {          // RNE float->bf16
  union { float f; unsigned u; } v; v.f = f;
  unsigned r = v.u + 0x7FFFu + ((v.u >> 16) & 1u);
  return (u16)(r >> 16);
}
__device__ inline u16 f2bf_rna(float f) {      // cheap round (f>=0)
  union { float f; unsigned u; } v; v.f = f;
  return (u16)((v.u + 0x8000u) >> 16);
}

// ---------------------------------------------------------------------------
// Fused prep: blocks [0,2304): XT[b*N+n][c] = bf16(x[b][c][n]) transpose tiles
//             blocks [2304,2624): fp32->bf16 weight convert (W1|W2|W3)
// ---------------------------------------------------------------------------
__global__ __launch_bounds__(256) void prep_kernel(
    const float* __restrict__ x, const float* __restrict__ w1,
    const float* __restrict__ w2, const float* __restrict__ w3,
    u16* __restrict__ XT, u16* __restrict__ W1b,
    u16* __restrict__ W2b, u16* __restrict__ W3b) {
  __shared__ float T[32][36];
  const int bx = blockIdx.x;
  const int t = threadIdx.x;
  if (bx < 2304) {
    const int n0 = (bx % 72) * 32, c0 = ((bx / 72) & 7) * 32, b = bx / 576;
    const int c = t >> 3, n4 = (t & 7) * 4;
    *(float4*)&T[c][n4] = *(const float4*)&x[((size_t)b * CC + c0 + c) * NN + n0 + n4];
    __syncthreads();
    const int nn = t >> 3, c4 = (t & 7) * 4;
    ushort4 o;
    o.x = f2bf(T[c4 + 0][nn]); o.y = f2bf(T[c4 + 1][nn]);
    o.z = f2bf(T[c4 + 2][nn]); o.w = f2bf(T[c4 + 3][nn]);
    *(ushort4*)&XT[((size_t)b * NN + n0 + nn) * CC + c0 + c4] = o;
  } else {
    const int i = ((bx - 2304) * 256 + t) * 4;
    const float* src; u16* dst; int off;
    if (i < 196608)      { src = w1; dst = W1b; off = i; }
    else if (i < 262144) { src = w2; dst = W2b; off = i - 196608; }
    else                 { src = w3; dst = W3b; off = i - 262144; }
    float4 v = *(const float4*)&src[off];
    ushort4 o = {f2bf(v.x), f2bf(v.y), f2bf(v.z), f2bf(v.w)};
    *(ushort4*)&dst[off] = o;
  }
}

// ---------------------------------------------------------------------------
// MFMA GEMM core 128x128 (R4/R8-proven, used by qkv): K=256, 4 waves 2x2.
// Frag layout (HW-verified): A row=ll, B col=ll, k=lh*8+j; C/D row=lh*4+r, col=ll.
// ---------------------------------------------------------------------------
__device__ __forceinline__ void gemm_core(
    const u16* __restrict__ act, const u16* __restrict__ wb,
    int m0, int j0, u16 (&As)[128][40], u16 (&Ws)[128][40],
    f32x4 (&acc)[4][4], int tid) {
  const int lane = tid & 63, ll = lane & 15, lh = lane >> 4;
  const int wv = tid >> 6;
  const int wm = (wv >> 1) << 6, wj = (wv & 1) << 6;
  const int r_ = tid >> 1;
  const int kh = (tid & 1) << 4;
  for (int k0 = 0; k0 < CC; k0 += 32) {
    __syncthreads();
    bf16x8 a0 = *(const bf16x8*)&act[(size_t)(m0 + r_) * CC + k0 + kh];
    bf16x8 a1 = *(const bf16x8*)&act[(size_t)(m0 + r_) * CC + k0 + kh + 8];
    bf16x8 w0 = *(const bf16x8*)&wb[(size_t)(j0 + r_) * CC + k0 + kh];
    bf16x8 w1 = *(const bf16x8*)&wb[(size_t)(j0 + r_) * CC + k0 + kh + 8];
    *(bf16x8*)&As[r_][kh]     = a0;
    *(bf16x8*)&As[r_][kh + 8] = a1;
    *(bf16x8*)&Ws[r_][kh]     = w0;
    *(bf16x8*)&Ws[r_][kh + 8] = w1;
    __syncthreads();
    bf16x8 af[4], bfv[4];
#pragma unroll
    for (int s = 0; s < 4; ++s) {
      af[s]  = *(const bf16x8*)&As[wm + s * 16 + ll][lh * 8];
      bfv[s] = *(const bf16x8*)&Ws[wj + s * 16 + ll][lh * 8];
    }
#pragma unroll
    for (int ms = 0; ms < 4; ++ms)
#pragma unroll
      for (int js = 0; js < 4; ++js)
        acc[ms][js] = __builtin_amdgcn_mfma_f32_16x16x32_bf16(af[ms], bfv[js], acc[ms][js], 0, 0, 0);
  }
}

// ---------------------------------------------------------------------------
// MFMA GEMM core 64x64 (outproj/conv). 4 waves 2x2, wave = 32x32. LDS 10 KB.
// ---------------------------------------------------------------------------
__device__ __forceinline__ void gemm_core64(
    const u16* __restrict__ act, const u16* __restrict__ wb,
    int m0, int j0, u16 (&As)[64][40], u16 (&Ws)[64][40],
    f32x4 (&acc)[2][2], int tid) {
  const int lane = tid & 63, ll = lane & 15, lh = lane >> 4;
  const int wv = tid >> 6;
  const int wm = (wv >> 1) << 5, wj = (wv & 1) << 5;
  const bool isW = (tid >= 128);
  const int r_ = (tid & 127) >> 1;
  const int kh = (tid & 1) << 4;
  const u16* src = isW ? &wb[(size_t)(j0 + r_) * CC + kh]
                       : &act[(size_t)(m0 + r_) * CC + kh];
  u16* dst = isW ? &Ws[r_][kh] : &As[r_][kh];
  for (int k0 = 0; k0 < CC; k0 += 32) {
    __syncthreads();
    bf16x8 v0 = *(const bf16x8*)(src + k0);
    bf16x8 v1 = *(const bf16x8*)(src + k0 + 8);
    *(bf16x8*)dst       = v0;
    *(bf16x8*)(dst + 8) = v1;
    __syncthreads();
    bf16x8 af[2], bfv[2];
#pragma unroll
    for (int s = 0; s < 2; ++s) {
      af[s]  = *(const bf16x8*)&As[wm + s * 16 + ll][lh * 8];
      bfv[s] = *(const bf16x8*)&Ws[wj + s * 16 + ll][lh * 8];
    }
#pragma unroll
    for (int ms = 0; ms < 2; ++ms)
#pragma unroll
      for (int js = 0; js < 2; ++js)
        acc[ms][js] = __builtin_amdgcn_mfma_f32_16x16x32_bf16(af[ms], bfv[js], acc[ms][js], 0, 0, 0);
  }
}

// ---------------------------------------------------------------------------
// GEMM 1 (128x128): qkv = XT @ W1^T + b1 -> Q, K [B,H,N,32], VT [B,H,32,N]
// (R14 epilogue: scalar Q/K stores — fire-and-forget, no extra barriers)
// ---------------------------------------------------------------------------
__global__ __launch_bounds__(256) void qkv_gemm(
    const u16* __restrict__ XT, const u16* __restrict__ W1b,
    const float* __restrict__ bias,
    u16* __restrict__ Qb, u16* __restrict__ Kb, u16* __restrict__ VTb) {
  __shared__ u16 As[128][40];
  __shared__ u16 Ws[128][40];
  const int tid = threadIdx.x;
  const int m0 = blockIdx.x * 128, j0 = blockIdx.y * 128;
  f32x4 acc[4][4] = {};
  gemm_core(XT, W1b, m0, j0, As, Ws, acc, tid);

  const int lane = tid & 63, ll = lane & 15, lh = lane >> 4;
  const int wv = tid >> 6;
  const int wm = (wv >> 1) << 6, wj = (wv & 1) << 6;
  const int part = blockIdx.y >> 1;            // 0=Q 1=K 2=V (uniform)
  const int b = m0 / NN, n0 = m0 % NN;
#pragma unroll
  for (int js = 0; js < 4; ++js) {
    const int j = j0 + wj + js * 16 + ll;
    const float bj = bias[j];
    const int head = (j >> 5) & 7, d = j & 31;
#pragma unroll
    for (int ms = 0; ms < 4; ++ms) {
      const int nb = n0 + wm + ms * 16 + (lh << 2);
      if (part == 2) {
        ushort4 v = {f2bf(acc[ms][js][0] + bj), f2bf(acc[ms][js][1] + bj),
                     f2bf(acc[ms][js][2] + bj), f2bf(acc[ms][js][3] + bj)};
        *(ushort4*)&VTb[(((size_t)b * NHEAD + head) * HD + d) * NN + nb] = v;
      } else {
        u16* dst = (part == 0 ? Qb : Kb) + ((size_t)b * NHEAD + head) * PLANE;
#pragma unroll
        for (int r = 0; r < 4; ++r)
          dst[(size_t)(nb + r) * HD + d] = f2bf(acc[ms][js][r] + bj);
      }
    }
  }
}

// ---------------------------------------------------------------------------
// MFMA windowed attention (R14-proven BEST): 16x4 query tile, 2-row chunked
// double-buffered staging, setprio around compute. LDS 22.3 KB.
// + XCD-aware bid swizzle (T1): each XCD gets 144 contiguous blocks = 4 whole
// (b,head) K/V planes -> plane-local L2 reuse. Bijective (1152 % 8 == 0).
// ---------------------------------------------------------------------------
__global__ __launch_bounds__(256) void attn_mfma(
    const u16* __restrict__ Qb, const u16* __restrict__ Kb,
    const u16* __restrict__ VTb, u16* __restrict__ Ob) {
  __shared__ u16 Ks[2][64][32];   // [buf][slot = rr*32+key][dim]
  __shared__ u16 VTs[2][32][72];  // [buf][dim][slot] (pad 72)
  __shared__ u16 Ps[4][16][40];   // per-wave P [query][keyslot]
  const int bid0 = blockIdx.x;
  const int bid  = (bid0 & 7) * 144 + (bid0 >> 3);   // XCD swizzle (bijective)
  const int tile = bid % 36;      // 12 (th) x 3 (tw)
  const int head = (bid / 36) & 7;
  const int b    = bid / 288;
  const int th0 = (tile / 3) * 4, tw0 = (tile % 3) * 16;
  const int tid = threadIdx.x;
  const int wv = tid >> 6, lane = tid & 63;
  const int lh = lane >> 4, ll = lane & 15;
  const size_t plane = ((size_t)b * NHEAD + head) * PLANE;

  const int wlo = max(0, tw0 - 8);
  const int nw  = min(WI, tw0 + 24) - wlo;       // 24 or 32, block-uniform
  const int rlo = max(0, th0 - 8), rhi = min(HH, th0 + 12);   // even count

  const int qh = th0 + wv;                       // wave's query row
  const bf16x8 qfrag = *(const bf16x8*)&Qb[plane + (size_t)(qh * WI + tw0 + ll) * HD + lh * 8];

  int qw_r[4];
  float cb0[4], cb1[4];
  const int wk0 = wlo + ll;
  const int wk1 = wlo + 16 + ll;
#pragma unroll
  for (int r = 0; r < 4; ++r) {
    qw_r[r] = tw0 + (lh << 2) + r;
    cb0[r] = (abs(wk0 - qw_r[r]) <= 8) ? 0.0f : -30000.0f;
    cb1[r] = (wk1 < WI && abs(wk1 - qw_r[r]) <= 8) ? 0.0f : -30000.0f;
  }

  f32x4 o0 = {0.f, 0.f, 0.f, 0.f}, o1 = {0.f, 0.f, 0.f, 0.f};
  const f32x4 zf = {0.f, 0.f, 0.f, 0.f};
  float lsum[4] = {0.f, 0.f, 0.f, 0.f};
  const int sk_slot = tid >> 2, sk_d = (tid & 3) * 8;
  const int sk_rr = sk_slot >> 5, sk_c = sk_slot & 31;
  const int sv_d = tid >> 3, sv_s = (tid & 7) * 8;
  const int sv_rr = sv_s >> 5, sv_c = sv_s & 31;
  const bf16x8 zz8 = {0, 0, 0, 0, 0, 0, 0, 0};
  const float C2 = 0.25501651847296056f;         // (1/sqrt(32)) * log2(e)
  const int nch = (rhi - rlo) >> 1;

  {
    bf16x8 kv = zz8, vv = zz8;
    if (sk_c < nw)
      kv = *(const bf16x8*)&Kb[plane + (size_t)((rlo + sk_rr) * WI + wlo + sk_c) * HD + sk_d];
    if (sv_c < nw)
      vv = *(const bf16x8*)&VTb[plane + (size_t)sv_d * NN + (rlo + sv_rr) * WI + wlo + sv_c];
    *(bf16x8*)&Ks[0][sk_slot][sk_d] = kv;
    *(bf16x8*)&VTs[0][sv_d][sv_s] = vv;
  }

  int cur = 0;
  for (int c = 0; c < nch; ++c) {
    const int hk2 = rlo + (c << 1);
    bf16x8 nkv = zz8, nvv = zz8;
    const bool more = (c + 1 < nch);
    if (more) {
      if (sk_c < nw)
        nkv = *(const bf16x8*)&Kb[plane + (size_t)((hk2 + 2 + sk_rr) * WI + wlo + sk_c) * HD + sk_d];
      if (sv_c < nw)
        nvv = *(const bf16x8*)&VTb[plane + (size_t)sv_d * NN + (hk2 + 2 + sv_rr) * WI + wlo + sv_c];
    }
    __syncthreads();   // buf[cur] complete
#pragma unroll
    for (int rr = 0; rr < 2; ++rr) {
      const int hk = hk2 + rr;
      if (hk >= qh - 8 && hk <= qh + 8) {          // wave-uniform row window
        const int sb = rr << 5;
        __builtin_amdgcn_s_setprio(1);
        const bf16x8 k0 = *(const bf16x8*)&Ks[cur][sb + ll][lh * 8];
        const bf16x8 k1 = *(const bf16x8*)&Ks[cur][sb + 16 + ll][lh * 8];
        f32x4 s0 = __builtin_amdgcn_mfma_f32_16x16x32_bf16(qfrag, k0, zf, 0, 0, 0);
        f32x4 s1 = __builtin_amdgcn_mfma_f32_16x16x32_bf16(qfrag, k1, zf, 0, 0, 0);
#pragma unroll
        for (int r = 0; r < 4; ++r) {
          float e0 = exp2f(fmaf(s0[r], C2, cb0[r]));
          float e1 = exp2f(fmaf(s1[r], C2, cb1[r]));
          lsum[r] += e0 + e1;
          Ps[wv][(lh << 2) + r][ll]      = f2bf_rna(e0);
          Ps[wv][(lh << 2) + r][16 + ll] = f2bf_rna(e1);
        }
        const bf16x8 pa = *(const bf16x8*)&Ps[wv][ll][lh * 8];
        const bf16x8 v0 = *(const bf16x8*)&VTs[cur][ll][sb + lh * 8];
        const bf16x8 v1 = *(const bf16x8*)&VTs[cur][16 + ll][sb + lh * 8];
        o0 = __builtin_amdgcn_mfma_f32_16x16x32_bf16(pa, v0, o0, 0, 0, 0);
        o1 = __builtin_amdgcn_mfma_f32_16x16x32_bf16(pa, v1, o1, 0, 0, 0);
        __builtin_amdgcn_s_setprio(0);
      }
    }
    if (more) {
      *(bf16x8*)&Ks[cur ^ 1][sk_slot][sk_d] = nkv;
      *(bf16x8*)&VTs[cur ^ 1][sv_d][sv_s] = nvv;
    }
    cur ^= 1;
  }

#pragma unroll
  for (int r = 0; r < 4; ++r) {
    float s = lsum[r];
    s += __shfl_xor(s, 1); s += __shfl_xor(s, 2);
    s += __shfl_xor(s, 4); s += __shfl_xor(s, 8);
    const float inv = 1.0f / s;
    const size_t row = ((size_t)b * NN + qh * WI + qw_r[r]) * CC + head * HD;
    Ob[row + ll]      = f2bf(o0[r] * inv);
    Ob[row + 16 + ll] = f2bf(o1[r] * inv);
  }
}

// ---------------------------------------------------------------------------
// GEMM 2 (64x64 tiles): RES[m][c] = bf16( O @ W2^T + b2 + x[b][c][n] )
// ---------------------------------------------------------------------------
__global__ __launch_bounds__(256) void outproj_gemm(
    const u16* __restrict__ Ob, const u16* __restrict__ W2b,
    const float* __restrict__ bias, const float* __restrict__ x,
    u16* __restrict__ RESb) {
  __shared__ u16 As[64][40];
  __shared__ u16 Ws[64][40];
  const int tid = threadIdx.x;
  const int m0 = blockIdx.x * 64, j0 = blockIdx.y * 64;
  f32x4 acc[2][2] = {};
  gemm_core64(Ob, W2b, m0, j0, As, Ws, acc, tid);

  const int lane = tid & 63, ll = lane & 15, lh = lane >> 4;
  const int wv = tid >> 6;
  const int wm = (wv >> 1) << 5, wj = (wv & 1) << 5;
  const int b = m0 / NN, n0 = m0 % NN;
#pragma unroll
  for (int js = 0; js < 2; ++js) {
    const int j = j0 + wj + js * 16 + ll;
    const float bj = bias[j];
#pragma unroll
    for (int ms = 0; ms < 2; ++ms) {
      const int nb = n0 + wm + ms * 16 + (lh << 2);
      float4 xr = *(const float4*)&x[((size_t)b * CC + j) * NN + nb];
      float rr[4] = {acc[ms][js][0] + bj + xr.x, acc[ms][js][1] + bj + xr.y,
                     acc[ms][js][2] + bj + xr.z, acc[ms][js][3] + bj + xr.w};
#pragma unroll
      for (int r = 0; r < 4; ++r)
        RESb[(size_t)(m0 + wm + ms * 16 + (lh << 2) + r) * CC + j] = f2bf(rr[r]);
    }
  }
}

// ---------------------------------------------------------------------------
// GEMM 3 (64x64 tiles): out[b][c][n] = relu( RES @ W3^T + b3 )  (fp32 output)
// ---------------------------------------------------------------------------
__global__ __launch_bounds__(256) void conv_gemm(
    const u16* __restrict__ RESb, const u16* __restrict__ W3b,
    const float* __restrict__ bias, float* __restrict__ out) {
  __shared__ u16 As[64][40];
  __shared__ u16 Ws[64][40];
  const int tid = threadIdx.x;
  const int m0 = blockIdx.x * 64, j0 = blockIdx.y * 64;
  f32x4 acc[2][2] = {};
  gemm_core64(RESb, W3b, m0, j0, As, Ws, acc, tid);

  const int lane = tid & 63, ll = lane & 15, lh = lane >> 4;
  const int wv = tid >> 6;
  const int wm = (wv >> 1) << 5, wj = (wv & 1) << 5;
  const int b = m0 / NN, n0 = m0 % NN;
#pragma unroll
  for (int js = 0; js < 2; ++js) {
    const int j = j0 + wj + js * 16 + ll;
    const float bj = bias[j];
#pragma unroll
    for (int ms = 0; ms < 2; ++ms) {
      const int nb = n0 + wm + ms * 16 + (lh << 2);
      float4 v;
      v.x = fmaxf(acc[ms][js][0] + bj, 0.0f);
      v.y = fmaxf(acc[ms][js][1] + bj, 0.0f);
      v.z = fmaxf(acc[ms][js][2] + bj, 0.0f);
      v.w = fmaxf(acc[ms][js][3] + bj, 0.0f);
      *(float4*)&out[((size_t)b * CC + j) * NN + nb] = v;
    }
  }
}

extern "C" void kernel_launch(void* const* d_in, const int* in_sizes, int n_in,
                              void* d_out, int out_size, void* d_ws, size_t ws_size,
                              hipStream_t stream) {
  const float* x         = (const float*)d_in[0];
  const float* in_proj_w = (const float*)d_in[1];
  const float* in_proj_b = (const float*)d_in[2];
  const float* out_w     = (const float*)d_in[3];
  const float* out_b     = (const float*)d_in[4];
  const float* conv_w    = (const float*)d_in[5];
  const float* conv_b    = (const float*)d_in[6];
  float* out = (float*)d_out;

  u16* wsb = (u16*)d_ws;
  u16* XT   = wsb;                         // [9216][256] bf16
  u16* Qb   = wsb + (size_t)BUF;           // [B,H,N,32]
  u16* Kb   = wsb + (size_t)2 * BUF;       // [B,H,N,32]
  u16* VTb  = wsb + (size_t)3 * BUF;       // [B,H,32,N]
  u16* Ob   = wsb + (size_t)4 * BUF;       // [9216][256]
  u16* RESb = wsb + (size_t)5 * BUF;       // [9216][256]
  u16* W1b  = wsb + (size_t)6 * BUF;       // [768][256]
  u16* W2b  = W1b + 196608;                // [256][256]
  u16* W3b  = W2b + 65536;                 // [256][256]

  prep_kernel<<<dim3(2624), dim3(256), 0, stream>>>(x, in_proj_w, out_w, conv_w,
                                                    XT, W1b, W2b, W3b);
  qkv_gemm<<<dim3(72, 6), dim3(256), 0, stream>>>(XT, W1b, in_proj_b, Qb, Kb, VTb);
  attn_mfma<<<dim3(1152), dim3(256), 0, stream>>>(Qb, Kb, VTb, Ob);
  outproj_gemm<<<dim3(144, 4), dim3(256), 0, stream>>>(Ob, W2b, out_b, x, RESb);
  conv_gemm<<<dim3(144, 4), dim3(256), 0, stream>>>(RESb, W3b, conv_b, out);
}

// Round 18
// 58.179 us; speedup vs baseline: 1.0786x; 1.0032x over previous
//
#include <hip/hip_runtime.h>
#include <math.h>

#define BB 4
#define CC 256
#define HH 48
#define WI 48
#define NN (HH*WI)      // 2304
#define NHEAD 8
#define HD 32
#define PLANE ((size_t)NN*HD)
#define BUF   (BB*NHEAD*NN*HD)      // 2359296 elems per [9216,256] buffer

typedef unsigned short u16;
typedef __attribute__((ext_vector_type(8))) short bf16x8;
typedef __attribute__((ext_vector_type(4))) float f32x4;

__device__ inline u16 f2bf(float f) {          // RNE float->bf16
  union { float f; unsigned u; } v; v.f = f;
  unsigned r = v.u + 0x7FFFu + ((v.u >> 16) & 1u);
  return (u16)(r >> 16);
}
__device__ inline u16 f2bf_rna(float f) {      // cheap round (f>=0)
  union { float f; unsigned u; } v; v.f = f;
  return (u16)((v.u + 0x8000u) >> 16);
}

// ---------------------------------------------------------------------------
// Fused prep: blocks [0,2304): XT[b*N+n][c] = bf16(x[b][c][n]) transpose tiles
//             blocks [2304,2624): fp32->bf16 weight convert (W1|W2|W3)
// ---------------------------------------------------------------------------
__global__ __launch_bounds__(256) void prep_kernel(
    const float* __restrict__ x, const float* __restrict__ w1,
    const float* __restrict__ w2, const float* __restrict__ w3,
    u16* __restrict__ XT, u16* __restrict__ W1b,
    u16* __restrict__ W2b, u16* __restrict__ W3b) {
  __shared__ float T[32][36];
  const int bx = blockIdx.x;
  const int t = threadIdx.x;
  if (bx < 2304) {
    const int n0 = (bx % 72) * 32, c0 = ((bx / 72) & 7) * 32, b = bx / 576;
    const int c = t >> 3, n4 = (t & 7) * 4;
    *(float4*)&T[c][n4] = *(const float4*)&x[((size_t)b * CC + c0 + c) * NN + n0 + n4];
    __syncthreads();
    const int nn = t >> 3, c4 = (t & 7) * 4;
    ushort4 o;
    o.x = f2bf(T[c4 + 0][nn]); o.y = f2bf(T[c4 + 1][nn]);
    o.z = f2bf(T[c4 + 2][nn]); o.w = f2bf(T[c4 + 3][nn]);
    *(ushort4*)&XT[((size_t)b * NN + n0 + nn) * CC + c0 + c4] = o;
  } else {
    const int i = ((bx - 2304) * 256 + t) * 4;
    const float* src; u16* dst; int off;
    if (i < 196608)      { src = w1; dst = W1b; off = i; }
    else if (i < 262144) { src = w2; dst = W2b; off = i - 196608; }
    else                 { src = w3; dst = W3b; off = i - 262144; }
    float4 v = *(const float4*)&src[off];
    ushort4 o = {f2bf(v.x), f2bf(v.y), f2bf(v.z), f2bf(v.w)};
    *(ushort4*)&dst[off] = o;
  }
}

// ---------------------------------------------------------------------------
// MFMA GEMM core 128x128 (R4/R8-proven, used by qkv): K=256, 4 waves 2x2.
// Frag layout (HW-verified): A row=ll, B col=ll, k=lh*8+j; C/D row=lh*4+r, col=ll.
// ---------------------------------------------------------------------------
__device__ __forceinline__ void gemm_core(
    const u16* __restrict__ act, const u16* __restrict__ wb,
    int m0, int j0, u16 (&As)[128][40], u16 (&Ws)[128][40],
    f32x4 (&acc)[4][4], int tid) {
  const int lane = tid & 63, ll = lane & 15, lh = lane >> 4;
  const int wv = tid >> 6;
  const int wm = (wv >> 1) << 6, wj = (wv & 1) << 6;
  const int r_ = tid >> 1;
  const int kh = (tid & 1) << 4;
  for (int k0 = 0; k0 < CC; k0 += 32) {
    __syncthreads();
    bf16x8 a0 = *(const bf16x8*)&act[(size_t)(m0 + r_) * CC + k0 + kh];
    bf16x8 a1 = *(const bf16x8*)&act[(size_t)(m0 + r_) * CC + k0 + kh + 8];
    bf16x8 w0 = *(const bf16x8*)&wb[(size_t)(j0 + r_) * CC + k0 + kh];
    bf16x8 w1 = *(const bf16x8*)&wb[(size_t)(j0 + r_) * CC + k0 + kh + 8];
    *(bf16x8*)&As[r_][kh]     = a0;
    *(bf16x8*)&As[r_][kh + 8] = a1;
    *(bf16x8*)&Ws[r_][kh]     = w0;
    *(bf16x8*)&Ws[r_][kh + 8] = w1;
    __syncthreads();
    bf16x8 af[4], bfv[4];
#pragma unroll
    for (int s = 0; s < 4; ++s) {
      af[s]  = *(const bf16x8*)&As[wm + s * 16 + ll][lh * 8];
      bfv[s] = *(const bf16x8*)&Ws[wj + s * 16 + ll][lh * 8];
    }
#pragma unroll
    for (int ms = 0; ms < 4; ++ms)
#pragma unroll
      for (int js = 0; js < 4; ++js)
        acc[ms][js] = __builtin_amdgcn_mfma_f32_16x16x32_bf16(af[ms], bfv[js], acc[ms][js], 0, 0, 0);
  }
}

// ---------------------------------------------------------------------------
// MFMA GEMM core 64x64 (outproj/conv). 4 waves 2x2, wave = 32x32. LDS 10 KB.
// ---------------------------------------------------------------------------
__device__ __forceinline__ void gemm_core64(
    const u16* __restrict__ act, const u16* __restrict__ wb,
    int m0, int j0, u16 (&As)[64][40], u16 (&Ws)[64][40],
    f32x4 (&acc)[2][2], int tid) {
  const int lane = tid & 63, ll = lane & 15, lh = lane >> 4;
  const int wv = tid >> 6;
  const int wm = (wv >> 1) << 5, wj = (wv & 1) << 5;
  const bool isW = (tid >= 128);
  const int r_ = (tid & 127) >> 1;
  const int kh = (tid & 1) << 4;
  const u16* src = isW ? &wb[(size_t)(j0 + r_) * CC + kh]
                       : &act[(size_t)(m0 + r_) * CC + kh];
  u16* dst = isW ? &Ws[r_][kh] : &As[r_][kh];
  for (int k0 = 0; k0 < CC; k0 += 32) {
    __syncthreads();
    bf16x8 v0 = *(const bf16x8*)(src + k0);
    bf16x8 v1 = *(const bf16x8*)(src + k0 + 8);
    *(bf16x8*)dst       = v0;
    *(bf16x8*)(dst + 8) = v1;
    __syncthreads();
    bf16x8 af[2], bfv[2];
#pragma unroll
    for (int s = 0; s < 2; ++s) {
      af[s]  = *(const bf16x8*)&As[wm + s * 16 + ll][lh * 8];
      bfv[s] = *(const bf16x8*)&Ws[wj + s * 16 + ll][lh * 8];
    }
#pragma unroll
    for (int ms = 0; ms < 2; ++ms)
#pragma unroll
      for (int js = 0; js < 2; ++js)
        acc[ms][js] = __builtin_amdgcn_mfma_f32_16x16x32_bf16(af[ms], bfv[js], acc[ms][js], 0, 0, 0);
  }
}

// ---------------------------------------------------------------------------
// GEMM 1 (128x128): qkv = XT @ W1^T + b1 -> Q, K [B,H,N,32], VT [B,H,32,N]
// ---------------------------------------------------------------------------
__global__ __launch_bounds__(256) void qkv_gemm(
    const u16* __restrict__ XT, const u16* __restrict__ W1b,
    const float* __restrict__ bias,
    u16* __restrict__ Qb, u16* __restrict__ Kb, u16* __restrict__ VTb) {
  __shared__ u16 As[128][40];
  __shared__ u16 Ws[128][40];
  const int tid = threadIdx.x;
  const int m0 = blockIdx.x * 128, j0 = blockIdx.y * 128;
  f32x4 acc[4][4] = {};
  gemm_core(XT, W1b, m0, j0, As, Ws, acc, tid);

  const int lane = tid & 63, ll = lane & 15, lh = lane >> 4;
  const int wv = tid >> 6;
  const int wm = (wv >> 1) << 6, wj = (wv & 1) << 6;
  const int part = blockIdx.y >> 1;            // 0=Q 1=K 2=V (uniform)
  const int b = m0 / NN, n0 = m0 % NN;
#pragma unroll
  for (int js = 0; js < 4; ++js) {
    const int j = j0 + wj + js * 16 + ll;
    const float bj = bias[j];
    const int head = (j >> 5) & 7, d = j & 31;
#pragma unroll
    for (int ms = 0; ms < 4; ++ms) {
      const int nb = n0 + wm + ms * 16 + (lh << 2);
      if (part == 2) {
        ushort4 v = {f2bf(acc[ms][js][0] + bj), f2bf(acc[ms][js][1] + bj),
                     f2bf(acc[ms][js][2] + bj), f2bf(acc[ms][js][3] + bj)};
        *(ushort4*)&VTb[(((size_t)b * NHEAD + head) * HD + d) * NN + nb] = v;
      } else {
        u16* dst = (part == 0 ? Qb : Kb) + ((size_t)b * NHEAD + head) * PLANE;
#pragma unroll
        for (int r = 0; r < 4; ++r)
          dst[(size_t)(nb + r) * HD + d] = f2bf(acc[ms][js][r] + bj);
      }
    }
  }
}

// ---------------------------------------------------------------------------
// MFMA windowed attention (R17-proven BEST): 16x4 query tile, 2-row chunked
// double-buffered staging, setprio, XCD swizzle. LDS 22.3 KB.
// NEW: clamped staging addresses replace per-lane predicates + zero-fill —
// clamped slots are exactly the mask-zeroed slots (verified per tw-tile),
// so output is bit-identical with fewer exec-mask ops in the staging path.
// ---------------------------------------------------------------------------
__global__ __launch_bounds__(256) void attn_mfma(
    const u16* __restrict__ Qb, const u16* __restrict__ Kb,
    const u16* __restrict__ VTb, u16* __restrict__ Ob) {
  __shared__ u16 Ks[2][64][32];   // [buf][slot = rr*32+key][dim]
  __shared__ u16 VTs[2][32][72];  // [buf][dim][slot] (pad 72)
  __shared__ u16 Ps[4][16][40];   // per-wave P [query][keyslot]
  const int bid0 = blockIdx.x;
  const int bid  = (bid0 & 7) * 144 + (bid0 >> 3);   // XCD swizzle (bijective)
  const int tile = bid % 36;      // 12 (th) x 3 (tw)
  const int head = (bid / 36) & 7;
  const int b    = bid / 288;
  const int th0 = (tile / 3) * 4, tw0 = (tile % 3) * 16;
  const int tid = threadIdx.x;
  const int wv = tid >> 6, lane = tid & 63;
  const int lh = lane >> 4, ll = lane & 15;
  const size_t plane = ((size_t)b * NHEAD + head) * PLANE;

  const int wlo = max(0, tw0 - 8);
  const int nw  = min(WI, tw0 + 24) - wlo;       // 24 or 32, block-uniform
  const int rlo = max(0, th0 - 8), rhi = min(HH, th0 + 12);   // even count

  const int qh = th0 + wv;                       // wave's query row
  const bf16x8 qfrag = *(const bf16x8*)&Qb[plane + (size_t)(qh * WI + tw0 + ll) * HD + lh * 8];

  int qw_r[4];
  float cb0[4], cb1[4];
  const int wk0 = wlo + ll;
  const int wk1 = wlo + 16 + ll;
#pragma unroll
  for (int r = 0; r < 4; ++r) {
    qw_r[r] = tw0 + (lh << 2) + r;
    cb0[r] = (abs(wk0 - qw_r[r]) <= 8) ? 0.0f : -30000.0f;
    cb1[r] = (wk1 < WI && abs(wk1 - qw_r[r]) <= 8) ? 0.0f : -30000.0f;
  }

  f32x4 o0 = {0.f, 0.f, 0.f, 0.f}, o1 = {0.f, 0.f, 0.f, 0.f};
  const f32x4 zf = {0.f, 0.f, 0.f, 0.f};
  float lsum[4] = {0.f, 0.f, 0.f, 0.f};
  // clamped staging columns: slots >= nw stage col nw-1 data; those slots
  // always have P=0 via cb masks, so values are irrelevant (finite).
  const int sk_slot = tid >> 2, sk_d = (tid & 3) * 8;
  const int sk_rr = sk_slot >> 5;
  const int sk_c  = min(sk_slot & 31, nw - 1);
  const int sv_d = tid >> 3, sv_s = (tid & 7) * 8;
  const int sv_rr = sv_s >> 5;
  const int sv_c  = min(sv_s & 31, nw - 1);
  const float C2 = 0.25501651847296056f;         // (1/sqrt(32)) * log2(e)
  const int nch = (rhi - rlo) >> 1;

  {
    bf16x8 kv = *(const bf16x8*)&Kb[plane + (size_t)((rlo + sk_rr) * WI + wlo + sk_c) * HD + sk_d];
    bf16x8 vv = *(const bf16x8*)&VTb[plane + (size_t)sv_d * NN + (rlo + sv_rr) * WI + wlo + sv_c];
    *(bf16x8*)&Ks[0][sk_slot][sk_d] = kv;
    *(bf16x8*)&VTs[0][sv_d][sv_s] = vv;
  }

  int cur = 0;
  for (int c = 0; c < nch; ++c) {
    const int hk2 = rlo + (c << 1);
    bf16x8 nkv, nvv;
    const bool more = (c + 1 < nch);
    if (more) {
      nkv = *(const bf16x8*)&Kb[plane + (size_t)((hk2 + 2 + sk_rr) * WI + wlo + sk_c) * HD + sk_d];
      nvv = *(const bf16x8*)&VTb[plane + (size_t)sv_d * NN + (hk2 + 2 + sv_rr) * WI + wlo + sv_c];
    }
    __syncthreads();   // buf[cur] complete
#pragma unroll
    for (int rr = 0; rr < 2; ++rr) {
      const int hk = hk2 + rr;
      if (hk >= qh - 8 && hk <= qh + 8) {          // wave-uniform row window
        const int sb = rr << 5;
        __builtin_amdgcn_s_setprio(1);
        const bf16x8 k0 = *(const bf16x8*)&Ks[cur][sb + ll][lh * 8];
        const bf16x8 k1 = *(const bf16x8*)&Ks[cur][sb + 16 + ll][lh * 8];
        f32x4 s0 = __builtin_amdgcn_mfma_f32_16x16x32_bf16(qfrag, k0, zf, 0, 0, 0);
        f32x4 s1 = __builtin_amdgcn_mfma_f32_16x16x32_bf16(qfrag, k1, zf, 0, 0, 0);
#pragma unroll
        for (int r = 0; r < 4; ++r) {
          float e0 = exp2f(fmaf(s0[r], C2, cb0[r]));
          float e1 = exp2f(fmaf(s1[r], C2, cb1[r]));
          lsum[r] += e0 + e1;
          Ps[wv][(lh << 2) + r][ll]      = f2bf_rna(e0);
          Ps[wv][(lh << 2) + r][16 + ll] = f2bf_rna(e1);
        }
        const bf16x8 pa = *(const bf16x8*)&Ps[wv][ll][lh * 8];
        const bf16x8 v0 = *(const bf16x8*)&VTs[cur][ll][sb + lh * 8];
        const bf16x8 v1 = *(const bf16x8*)&VTs[cur][16 + ll][sb + lh * 8];
        o0 = __builtin_amdgcn_mfma_f32_16x16x32_bf16(pa, v0, o0, 0, 0, 0);
        o1 = __builtin_amdgcn_mfma_f32_16x16x32_bf16(pa, v1, o1, 0, 0, 0);
        __builtin_amdgcn_s_setprio(0);
      }
    }
    if (more) {
      *(bf16x8*)&Ks[cur ^ 1][sk_slot][sk_d] = nkv;
      *(bf16x8*)&VTs[cur ^ 1][sv_d][sv_s] = nvv;
    }
    cur ^= 1;
  }

#pragma unroll
  for (int r = 0; r < 4; ++r) {
    float s = lsum[r];
    s += __shfl_xor(s, 1); s += __shfl_xor(s, 2);
    s += __shfl_xor(s, 4); s += __shfl_xor(s, 8);
    const float inv = 1.0f / s;
    const size_t row = ((size_t)b * NN + qh * WI + qw_r[r]) * CC + head * HD;
    Ob[row + ll]      = f2bf(o0[r] * inv);
    Ob[row + 16 + ll] = f2bf(o1[r] * inv);
  }
}

// ---------------------------------------------------------------------------
// GEMM 2 (64x64 tiles): RES[m][c] = bf16( O @ W2^T + b2 + x[b][c][n] )
// ---------------------------------------------------------------------------
__global__ __launch_bounds__(256) void outproj_gemm(
    const u16* __restrict__ Ob, const u16* __restrict__ W2b,
    const float* __restrict__ bias, const float* __restrict__ x,
    u16* __restrict__ RESb) {
  __shared__ u16 As[64][40];
  __shared__ u16 Ws[64][40];
  const int tid = threadIdx.x;
  const int m0 = blockIdx.x * 64, j0 = blockIdx.y * 64;
  f32x4 acc[2][2] = {};
  gemm_core64(Ob, W2b, m0, j0, As, Ws, acc, tid);

  const int lane = tid & 63, ll = lane & 15, lh = lane >> 4;
  const int wv = tid >> 6;
  const int wm = (wv >> 1) << 5, wj = (wv & 1) << 5;
  const int b = m0 / NN, n0 = m0 % NN;
#pragma unroll
  for (int js = 0; js < 2; ++js) {
    const int j = j0 + wj + js * 16 + ll;
    const float bj = bias[j];
#pragma unroll
    for (int ms = 0; ms < 2; ++ms) {
      const int nb = n0 + wm + ms * 16 + (lh << 2);
      float4 xr = *(const float4*)&x[((size_t)b * CC + j) * NN + nb];
      float rr[4] = {acc[ms][js][0] + bj + xr.x, acc[ms][js][1] + bj + xr.y,
                     acc[ms][js][2] + bj + xr.z, acc[ms][js][3] + bj + xr.w};
#pragma unroll
      for (int r = 0; r < 4; ++r)
        RESb[(size_t)(m0 + wm + ms * 16 + (lh << 2) + r) * CC + j] = f2bf(rr[r]);
    }
  }
}

// ---------------------------------------------------------------------------
// GEMM 3 (64x64 tiles): out[b][c][n] = relu( RES @ W3^T + b3 )  (fp32 output)
// ---------------------------------------------------------------------------
__global__ __launch_bounds__(256) void conv_gemm(
    const u16* __restrict__ RESb, const u16* __restrict__ W3b,
    const float* __restrict__ bias, float* __restrict__ out) {
  __shared__ u16 As[64][40];
  __shared__ u16 Ws[64][40];
  const int tid = threadIdx.x;
  const int m0 = blockIdx.x * 64, j0 = blockIdx.y * 64;
  f32x4 acc[2][2] = {};
  gemm_core64(RESb, W3b, m0, j0, As, Ws, acc, tid);

  const int lane = tid & 63, ll = lane & 15, lh = lane >> 4;
  const int wv = tid >> 6;
  const int wm = (wv >> 1) << 5, wj = (wv & 1) << 5;
  const int b = m0 / NN, n0 = m0 % NN;
#pragma unroll
  for (int js = 0; js < 2; ++js) {
    const int j = j0 + wj + js * 16 + ll;
    const float bj = bias[j];
#pragma unroll
    for (int ms = 0; ms < 2; ++ms) {
      const int nb = n0 + wm + ms * 16 + (lh << 2);
      float4 v;
      v.x = fmaxf(acc[ms][js][0] + bj, 0.0f);
      v.y = fmaxf(acc[ms][js][1] + bj, 0.0f);
      v.z = fmaxf(acc[ms][js][2] + bj, 0.0f);
      v.w = fmaxf(acc[ms][js][3] + bj, 0.0f);
      *(float4*)&out[((size_t)b * CC + j) * NN + nb] = v;
    }
  }
}

extern "C" void kernel_launch(void* const* d_in, const int* in_sizes, int n_in,
                              void* d_out, int out_size, void* d_ws, size_t ws_size,
                              hipStream_t stream) {
  const float* x         = (const float*)d_in[0];
  const float* in_proj_w = (const float*)d_in[1];
  const float* in_proj_b = (const float*)d_in[2];
  const float* out_w     = (const float*)d_in[3];
  const float* out_b     = (const float*)d_in[4];
  const float* conv_w    = (const float*)d_in[5];
  const float* conv_b    = (const float*)d_in[6];
  float* out = (float*)d_out;

  u16* wsb = (u16*)d_ws;
  u16* XT   = wsb;                         // [9216][256] bf16
  u16* Qb   = wsb + (size_t)BUF;           // [B,H,N,32]
  u16* Kb   = wsb + (size_t)2 * BUF;       // [B,H,N,32]
  u16* VTb  = wsb + (size_t)3 * BUF;       // [B,H,32,N]
  u16* Ob   = wsb + (size_t)4 * BUF;       // [9216][256]
  u16* RESb = wsb + (size_t)5 * BUF;       // [9216][256]
  u16* W1b  = wsb + (size_t)6 * BUF;       // [768][256]
  u16* W2b  = W1b + 196608;                // [256][256]
  u16* W3b  = W2b + 65536;                 // [256][256]

  prep_kernel<<<dim3(2624), dim3(256), 0, stream>>>(x, in_proj_w, out_w, conv_w,
                                                    XT, W1b, W2b, W3b);
  qkv_gemm<<<dim3(72, 6), dim3(256), 0, stream>>>(XT, W1b, in_proj_b, Qb, Kb, VTb);
  attn_mfma<<<dim3(1152), dim3(256), 0, stream>>>(Qb, Kb, VTb, Ob);
  outproj_gemm<<<dim3(144, 4), dim3(256), 0, stream>>>(Ob, W2b, out_b, x, RESb);
  conv_gemm<<<dim3(144, 4), dim3(256), 0, stream>>>(RESb, W3b, conv_b, out);
}